// Round 3
// baseline (324.539 us; speedup 1.0000x reference)
//
#include <hip/hip_runtime.h>
#include <math.h>

typedef _Float16 half8  __attribute__((ext_vector_type(8)));
typedef _Float16 half4  __attribute__((ext_vector_type(4)));
typedef float    float4v __attribute__((ext_vector_type(4)));

#define NDIM   16
#define HID    128
#define NSTEP  10
#define RPW    2            // parents per workgroup; grid = 1024/RPW = 512 -> 2 WGs/CU
#define NROWS  48           // 4 primal + 12 pad + 32 tangent rows (3 tiles of 16)
#define XSTR   136          // LDS activation row stride in halves (16B-aligned rows)
#define SBS    17           // fp32 state row stride (kills dword bank conflicts)

__device__ __forceinline__ float tanh_fast(float v) {
  // no clamp needed: e->inf => h->1 ; e->0 => h->-1
  float e = __expf(2.f * v);
  return 1.f - 2.f / (e + 1.f);
}

// 4 waves/WG, wave mi owns M-tiles {2mi, 2mi+1} (32 neurons) and ALL 3 N-tiles:
// nt0 = primal rows 0..15, nt1 = parent-0 tangents 16..31, nt2 = parent-1 tangents 32..47.
// tanh' broadcast parent p -> tangent rows is an intra-wave shfl (primal computed once/wave).
// 2 WGs/CU (two independent barrier domains) fill each other's barrier-drain bubbles.
__global__ __launch_bounds__(256, 2)
void flow_ode_kernel(const float* __restrict__ gx,  const float* __restrict__ gxs,
                     const float* __restrict__ W0,  const float* __restrict__ b0,
                     const float* __restrict__ W1,  const float* __restrict__ b1,
                     const float* __restrict__ W2,  const float* __restrict__ b2,
                     const float* __restrict__ W3,  const float* __restrict__ b3,
                     const float* __restrict__ W4,  const float* __restrict__ b4,
                     float* __restrict__ out)
{
  __shared__ __align__(16) _Float16 XT[2][NROWS][XSTR];
  __shared__ float Sb[NROWS][SBS];   // base state: z (primal rows) / J columns (tangent rows)
  __shared__ float Sa[NROWS][SBS];   // RK accumulator

  const int tid  = threadIdx.x;
  const int mi   = tid >> 6;     // wave index = M-group
  const int lane = tid & 63;
  const int q    = lane >> 4;
  const int ln   = lane & 15;
  const int g0   = blockIdx.x * RPW;

  // ---------------- weight fragments in registers ----------------
  half8 A0[2];
  half8 A1[2][4], A2[2][4], A3[2][4];
  half8 A4[4];
  float bw[4][2][4];
  float b4r[4];

  #pragma unroll
  for (int mt = 0; mt < 2; ++mt) {
    const int m = 32*mi + 16*mt + ln;
    #pragma unroll
    for (int j = 0; j < 8; ++j) {
      const int k = 8*q + j;
      A0[mt][j] = (k < NDIM+1) ? (_Float16)W0[k*HID + m] : (_Float16)0.f;
    }
    #pragma unroll
    for (int ks = 0; ks < 4; ++ks) {
      #pragma unroll
      for (int j = 0; j < 8; ++j) {
        const int k = 32*ks + 8*q + j;
        A1[mt][ks][j] = (_Float16)W1[k*HID + m];
        A2[mt][ks][j] = (_Float16)W2[k*HID + m];
        A3[mt][ks][j] = (_Float16)W3[k*HID + m];
      }
    }
  }
  #pragma unroll
  for (int ks = 0; ks < 4; ++ks)
    #pragma unroll
    for (int j = 0; j < 8; ++j)
      A4[ks][j] = (_Float16)W4[(32*ks + 8*q + j)*NDIM + ln];

  #pragma unroll
  for (int mt = 0; mt < 2; ++mt)
    #pragma unroll
    for (int r = 0; r < 4; ++r) {
      const int m = 32*mi + 16*mt + 4*q + r;
      bw[0][mt][r] = b0[m];
      bw[1][mt][r] = b1[m];
      bw[2][mt][r] = b2[m];
      bw[3][mt][r] = b3[m];
    }
  #pragma unroll
  for (int r = 0; r < 4; ++r) b4r[r] = b4[4*q + r];

  // ---------------- init state ----------------
  // rows 0,1: x parents; 2,3: x_star; 4..15 pad; 16+16p+j: tangent e_j of parent p
  for (int idx = tid; idx < NROWS*NDIM; idx += 256) {
    const int row = idx >> 4, i = idx & 15;
    float v = 0.f;
    if      (row < RPW)     v = gx [(g0 + row)*NDIM + i];
    else if (row < 2*RPW)   v = gxs[(g0 + row - RPW)*NDIM + i];
    else if (row >= 16)     v = (((row - 16) & 15) == i) ? 1.f : 0.f;
    Sb[row][i] = v;
    Sa[row][i] = 0.f;
    XT[0][row][i] = (_Float16)v;
  }
  for (int idx = tid; idx < NROWS*16; idx += 256) {
    const int row = idx >> 4;
    XT[0][row][16 + (idx & 15)] = (_Float16)0.f;
  }
  __syncthreads();

  const float dt = 1.f / NSTEP;
  int xb = 0;

  // epilogue: tile 0 = primal (tanh); tiles 1,2 = tangents scaled by parent's (1-h^2)
  auto finish = [&](float4v (&D)[2][3], const float (&bb)[2][4]) {
    #pragma unroll
    for (int mt = 0; mt < 2; ++mt) {
      float ss[4];
      half4 hh;
      #pragma unroll
      for (int r = 0; r < 4; ++r) {
        float h = tanh_fast(D[mt][0][r] + bb[mt][r]);
        hh[r] = (_Float16)h;
        ss[r] = 1.f - h*h;
      }
      *(half4*)&XT[xb^1][ln][32*mi + 16*mt + 4*q] = hh;
      #pragma unroll
      for (int nt = 1; nt < 3; ++nt) {            // parent p = nt-1 sits in lane (q, p)
        half4 tt;
        #pragma unroll
        for (int r = 0; r < 4; ++r) {
          float s = __shfl(ss[r], (lane & 48) + (nt - 1), 64);
          tt[r] = (_Float16)(D[mt][nt][r] * s);
        }
        *(half4*)&XT[xb^1][nt*16 + ln][32*mi + 16*mt + 4*q] = tt;
      }
    }
    __syncthreads();
    xb ^= 1;
  };

  auto mid_layer = [&](const half8 (&A)[2][4], const float (&bb)[2][4]) {
    float4v D[2][3];
    #pragma unroll
    for (int mt = 0; mt < 2; ++mt)
      #pragma unroll
      for (int nt = 0; nt < 3; ++nt)
        #pragma unroll
        for (int e = 0; e < 4; ++e) D[mt][nt][e] = 0.f;
    #pragma unroll
    for (int ks = 0; ks < 4; ++ks) {
      half8 Bf[3];
      #pragma unroll
      for (int nt = 0; nt < 3; ++nt)
        Bf[nt] = *(const half8*)&XT[xb][nt*16 + ln][32*ks + 8*q];
      #pragma unroll
      for (int nt = 0; nt < 3; ++nt) {
        D[0][nt] = __builtin_amdgcn_mfma_f32_16x16x32_f16(A[0][ks], Bf[nt], D[0][nt], 0, 0, 0);
        D[1][nt] = __builtin_amdgcn_mfma_f32_16x16x32_f16(A[1][ks], Bf[nt], D[1][nt], 0, 0, 0);
      }
    }
    finish(D, bb);
  };

  // layer-4 epilogue: RK4 state update + next stage's layer-0 input
  auto rk_update = [&](float4v D, int nt, int stage, float t0) {
    const int row = nt*16 + ln;
    const bool primal = (row < 2*RPW);
    const float w_s   = (stage == 1 || stage == 2) ? 2.f : 1.f;
    const float c_s   = (stage < 2) ? 0.5f*dt : dt;
    const float tnext = t0 + ((stage < 2) ? 0.5f*dt : dt);
    half4 xn;
    #pragma unroll
    for (int r = 0; r < 4; ++r) {
      const int j = 4*q + r;
      const float v = D[r] + (primal ? b4r[r] : 0.f);
      if (stage < 3) {
        Sa[row][j] += w_s * v;
        xn[r] = (_Float16)(Sb[row][j] + c_s * v);
      } else {
        const float nb = Sb[row][j] + (dt * (1.f/6.f)) * (Sa[row][j] + v);
        Sb[row][j] = nb;
        Sa[row][j] = 0.f;
        xn[r] = (_Float16)nb;
      }
    }
    *(half4*)&XT[xb^1][row][4*q] = xn;
    if (q == 0) {
      half8 z;
      #pragma unroll
      for (int j = 0; j < 8; ++j) z[j] = (_Float16)0.f;
      z[0] = (_Float16)(primal ? tnext : 0.f);
      *(half8*)&XT[xb^1][row][16] = z;
    } else if (q == 1) {
      half8 z;
      #pragma unroll
      for (int j = 0; j < 8; ++j) z[j] = (_Float16)0.f;
      *(half8*)&XT[xb^1][row][24] = z;
    }
  };

  // ---------------- 10 RK4 steps x 4 stages ----------------
  #pragma unroll 1
  for (int step = 0; step < NSTEP; ++step) {
    const float t0 = step * dt;
    #pragma unroll 1
    for (int stage = 0; stage < 4; ++stage) {
      { // ---- layer 0 (K = 32, single k-step) ----
        float4v D[2][3];
        #pragma unroll
        for (int mt = 0; mt < 2; ++mt)
          #pragma unroll
          for (int nt = 0; nt < 3; ++nt)
            #pragma unroll
            for (int e = 0; e < 4; ++e) D[mt][nt][e] = 0.f;
        half8 Bf[3];
        #pragma unroll
        for (int nt = 0; nt < 3; ++nt)
          Bf[nt] = *(const half8*)&XT[xb][nt*16 + ln][8*q];
        #pragma unroll
        for (int nt = 0; nt < 3; ++nt) {
          D[0][nt] = __builtin_amdgcn_mfma_f32_16x16x32_f16(A0[0], Bf[nt], D[0][nt], 0, 0, 0);
          D[1][nt] = __builtin_amdgcn_mfma_f32_16x16x32_f16(A0[1], Bf[nt], D[1][nt], 0, 0, 0);
        }
        finish(D, bw[0]);
      }
      mid_layer(A1, bw[1]);
      mid_layer(A2, bw[2]);
      mid_layer(A3, bw[3]);
      { // ---- layer 4 (N = 16): waves 0..2 each own one row-tile ----
        if (mi < 3) {
          float4v Da;
          #pragma unroll
          for (int e = 0; e < 4; ++e) Da[e] = 0.f;
          #pragma unroll
          for (int ks = 0; ks < 4; ++ks) {
            half8 Ba = *(const half8*)&XT[xb][mi*16 + ln][32*ks + 8*q];
            Da = __builtin_amdgcn_mfma_f32_16x16x32_f16(A4[ks], Ba, Da, 0, 0, 0);
          }
          rk_update(Da, mi, stage, t0);
        }
        __syncthreads();
        xb ^= 1;
      }
    }
  }

  // ---------------- per-parent solve: x_dot = -(J^T J + 1e-6 I)^{-1} J^T g ----------------
  if (mi < RPW) {
    const int p    = mi;
    const int jj   = ln;
    const int base = lane & 48;
    float c[NDIM], gv[NDIM], G[NDIM];
    #pragma unroll
    for (int i = 0; i < NDIM; ++i) c[i] = Sb[16 + 16*p + jj][i];
    float n2 = 0.f;
    #pragma unroll
    for (int i = 0; i < NDIM; ++i) {
      gv[i] = Sb[p][i] - Sb[RPW + p][i];
      n2 += gv[i]*gv[i];
    }
    const float rinv = 1.f / (sqrtf(n2) + 1e-8f);
    float rhs = 0.f;
    #pragma unroll
    for (int i = 0; i < NDIM; ++i) rhs += c[i] * gv[i];
    rhs *= rinv;
    #pragma unroll
    for (int k = 0; k < NDIM; ++k) {
      float acc = (k == jj) ? 1e-6f : 0.f;
      #pragma unroll
      for (int i = 0; i < NDIM; ++i)
        acc += c[i] * __shfl(c[i], base + k, 64);
      G[k] = acc;
    }
    #pragma unroll
    for (int k = 0; k < NDIM-1; ++k) {
      const float piv  = __shfl(G[k], base + k, 64);
      const float prhs = __shfl(rhs,  base + k, 64);
      const float f = (jj > k) ? G[k] / piv : 0.f;
      #pragma unroll
      for (int cc = k; cc < NDIM; ++cc)
        G[cc] -= f * __shfl(G[cc], base + k, 64);
      rhs -= f * prhs;
    }
    float sol = 0.f;
    #pragma unroll
    for (int k = NDIM-1; k >= 0; --k) {
      const float piv = __shfl(G[k], base + k, 64);
      const float pr  = __shfl(rhs,  base + k, 64);
      const float xk  = pr / piv;
      if (jj == k) sol = xk;
      if (jj <  k) rhs -= G[k] * xk;
    }
    if (lane < NDIM)
      out[(g0 + p)*NDIM + jj] = -sol;
  }
}

extern "C" void kernel_launch(void* const* d_in, const int* in_sizes, int n_in,
                              void* d_out, int out_size, void* d_ws, size_t ws_size,
                              hipStream_t stream) {
  (void)in_sizes; (void)n_in; (void)d_ws; (void)ws_size; (void)out_size;
  flow_ode_kernel<<<dim3(512), dim3(256), 0, stream>>>(
      (const float*)d_in[0],  (const float*)d_in[1],
      (const float*)d_in[2],  (const float*)d_in[3],
      (const float*)d_in[4],  (const float*)d_in[5],
      (const float*)d_in[6],  (const float*)d_in[7],
      (const float*)d_in[8],  (const float*)d_in[9],
      (const float*)d_in[10], (const float*)d_in[11],
      (float*)d_out);
}

// Round 4
// 287.177 us; speedup vs baseline: 1.1301x; 1.1301x over previous
//
#include <hip/hip_runtime.h>
#include <math.h>

typedef _Float16 half8  __attribute__((ext_vector_type(8)));
typedef _Float16 half4  __attribute__((ext_vector_type(4)));
typedef float    float4v __attribute__((ext_vector_type(4)));

#define NDIM   16
#define HID    128
#define NSTEP  10
#define RPW    2            // parents per WG; grid = 512 -> 2 WGs/CU
#define NROWS  48           // tile0: [x0,x1,xs0,xs1]x4 dup-primal; tiles 1,2: tangents of p=0,1
#define XSTR   136          // hidden-activation row stride (halves)
#define XISTR  40           // layer-0 input row stride (halves), 16B-aligned rows
#define SBS    17           // final-state row stride (fp32)

__device__ __forceinline__ float tanh_fast(float v) {
  float e = __expf(2.f * v);
  return 1.f - 2.f / (e + 1.f);
}

// broadcast lane (4g+P) -> lanes 4g..4g+3 via DPP quad_perm (VALU pipe, no LDS)
template<int CTRL>
__device__ __forceinline__ float qbcast(float v) {
  int i = __builtin_amdgcn_update_dpp(0, __builtin_bit_cast(int, v), CTRL, 0xF, 0xF, true);
  return __builtin_bit_cast(float, i);
}

// 4 waves/WG; wave mi owns neurons 32mi..32mi+31 (2 M-tiles) and computes all 3 N-tiles.
// Tile0 rows duplicated [x0,x1,xs0,xs1]x4 so tanh' broadcast is quad_perm (not ds_bpermute).
// RK4 state lives in registers of the tile-owning wave; LDS only for activations.
__global__ __launch_bounds__(256, 2)
void flow_ode_kernel(const float* __restrict__ gx,  const float* __restrict__ gxs,
                     const float* __restrict__ W0,  const float* __restrict__ b0,
                     const float* __restrict__ W1,  const float* __restrict__ b1,
                     const float* __restrict__ W2,  const float* __restrict__ b2,
                     const float* __restrict__ W3,  const float* __restrict__ b3,
                     const float* __restrict__ W4,  const float* __restrict__ b4,
                     float* __restrict__ out)
{
  __shared__ __align__(16) _Float16 XT[2][NROWS][XSTR];  // hidden activations ping-pong
  __shared__ __align__(16) _Float16 XI[NROWS][XISTR];    // layer-0 input (single buffer)
  __shared__ float SbL[NROWS][SBS];                      // final state (solve only)

  const int tid  = threadIdx.x;
  const int mi   = tid >> 6;
  const int lane = tid & 63;
  const int q    = lane >> 4;
  const int ln   = lane & 15;
  const int g0   = blockIdx.x * RPW;

  // ---------------- weight fragments in registers ----------------
  half8 A0[2];
  half8 A1[2][4], A2[2][4], A3[2][4];
  half8 A4[4];
  float bw[4][2][4];
  float b4r[4];

  #pragma unroll
  for (int mt = 0; mt < 2; ++mt) {
    const int m = 32*mi + 16*mt + ln;
    #pragma unroll
    for (int j = 0; j < 8; ++j) {
      const int k = 8*q + j;
      A0[mt][j] = (k < NDIM+1) ? (_Float16)W0[k*HID + m] : (_Float16)0.f;
    }
    #pragma unroll
    for (int ks = 0; ks < 4; ++ks) {
      #pragma unroll
      for (int j = 0; j < 8; ++j) {
        const int k = 32*ks + 8*q + j;
        A1[mt][ks][j] = (_Float16)W1[k*HID + m];
        A2[mt][ks][j] = (_Float16)W2[k*HID + m];
        A3[mt][ks][j] = (_Float16)W3[k*HID + m];
      }
    }
  }
  #pragma unroll
  for (int ks = 0; ks < 4; ++ks)
    #pragma unroll
    for (int j = 0; j < 8; ++j)
      A4[ks][j] = (_Float16)W4[(32*ks + 8*q + j)*NDIM + ln];

  #pragma unroll
  for (int mt = 0; mt < 2; ++mt)
    #pragma unroll
    for (int r = 0; r < 4; ++r) {
      const int m = 32*mi + 16*mt + 4*q + r;
      bw[0][mt][r] = b0[m];
      bw[1][mt][r] = b1[m];
      bw[2][mt][r] = b2[m];
      bw[3][mt][r] = b3[m];
    }
  #pragma unroll
  for (int r = 0; r < 4; ++r) b4r[r] = b4[4*q + r];

  // ---------------- RK state in registers ----------------
  // wave mi (<3) owns tile mi; lane (q,ln): row ln, dims 4q+r.
  float sbr[4], sar[4];
  if (mi == 0) {
    const int p = ln & 3;                                // [x0,x1,xs0,xs1] pattern
    const float* src = (p < 2) ? (gx + (g0 + p)*NDIM) : (gxs + (g0 + p - 2)*NDIM);
    #pragma unroll
    for (int r = 0; r < 4; ++r) sbr[r] = src[4*q + r];
  } else {
    #pragma unroll
    for (int r = 0; r < 4; ++r) sbr[r] = (ln == 4*q + r) ? 1.f : 0.f;  // tangent e_ln
  }
  #pragma unroll
  for (int r = 0; r < 4; ++r) sar[r] = 0.f;

  // ---------------- init XI (cols 0..31; 16..31 zeroed once, t(=0) included) ----------------
  for (int idx = tid; idx < NROWS*32; idx += 256)
    XI[idx >> 5][idx & 31] = (_Float16)0.f;
  __syncthreads();
  if (mi < 3) {
    half4 x4;
    #pragma unroll
    for (int r = 0; r < 4; ++r) x4[r] = (_Float16)sbr[r];
    *(half4*)&XI[mi*16 + ln][4*q] = x4;
  }
  __syncthreads();

  const float dt = 1.f / NSTEP;
  int xb = 0;

  // epilogue: tile0 -> tanh; tiles 1,2 -> scale by quad_perm-broadcast (1-h^2) of parent
  auto finish = [&](float4v (&D)[2][3], const float (&bb)[2][4]) {
    #pragma unroll
    for (int mt = 0; mt < 2; ++mt) {
      float ss[4];
      half4 hh;
      #pragma unroll
      for (int r = 0; r < 4; ++r) {
        float h = tanh_fast(D[mt][0][r] + bb[mt][r]);
        hh[r] = (_Float16)h;
        ss[r] = 1.f - h*h;
      }
      *(half4*)&XT[xb^1][ln][32*mi + 16*mt + 4*q] = hh;
      half4 t1, t2;
      #pragma unroll
      for (int r = 0; r < 4; ++r)
        t1[r] = (_Float16)(D[mt][1][r] * qbcast<0x00>(ss[r]));   // parent 0
      *(half4*)&XT[xb^1][16 + ln][32*mi + 16*mt + 4*q] = t1;
      #pragma unroll
      for (int r = 0; r < 4; ++r)
        t2[r] = (_Float16)(D[mt][2][r] * qbcast<0x55>(ss[r]));   // parent 1
      *(half4*)&XT[xb^1][32 + ln][32*mi + 16*mt + 4*q] = t2;
    }
    __syncthreads();
    xb ^= 1;
  };

  auto mid_layer = [&](const half8 (&A)[2][4], const float (&bb)[2][4]) {
    float4v D[2][3];
    #pragma unroll
    for (int mt = 0; mt < 2; ++mt)
      #pragma unroll
      for (int nt = 0; nt < 3; ++nt)
        #pragma unroll
        for (int e = 0; e < 4; ++e) D[mt][nt][e] = 0.f;
    #pragma unroll
    for (int ks = 0; ks < 4; ++ks) {
      half8 Bf[3];
      #pragma unroll
      for (int nt = 0; nt < 3; ++nt)
        Bf[nt] = *(const half8*)&XT[xb][nt*16 + ln][32*ks + 8*q];
      #pragma unroll
      for (int nt = 0; nt < 3; ++nt) {
        D[0][nt] = __builtin_amdgcn_mfma_f32_16x16x32_f16(A[0][ks], Bf[nt], D[0][nt], 0, 0, 0);
        D[1][nt] = __builtin_amdgcn_mfma_f32_16x16x32_f16(A[1][ks], Bf[nt], D[1][nt], 0, 0, 0);
      }
    }
    finish(D, bb);
  };

  // ---------------- 10 RK4 steps x 4 stages ----------------
  #pragma unroll 1
  for (int step = 0; step < NSTEP; ++step) {
    const float t0 = step * dt;
    #pragma unroll 1
    for (int stage = 0; stage < 4; ++stage) {
      { // ---- layer 0 (K = 32 from XI) ----
        float4v D[2][3];
        #pragma unroll
        for (int mt = 0; mt < 2; ++mt)
          #pragma unroll
          for (int nt = 0; nt < 3; ++nt)
            #pragma unroll
            for (int e = 0; e < 4; ++e) D[mt][nt][e] = 0.f;
        half8 Bf[3];
        #pragma unroll
        for (int nt = 0; nt < 3; ++nt)
          Bf[nt] = *(const half8*)&XI[nt*16 + ln][8*q];
        #pragma unroll
        for (int nt = 0; nt < 3; ++nt) {
          D[0][nt] = __builtin_amdgcn_mfma_f32_16x16x32_f16(A0[0], Bf[nt], D[0][nt], 0, 0, 0);
          D[1][nt] = __builtin_amdgcn_mfma_f32_16x16x32_f16(A0[1], Bf[nt], D[1][nt], 0, 0, 0);
        }
        finish(D, bw[0]);
      }
      mid_layer(A1, bw[1]);
      mid_layer(A2, bw[2]);
      mid_layer(A3, bw[3]);
      { // ---- layer 4 + RK update (waves 0..2 own their tiles) ----
        if (mi < 3) {
          float4v Da;
          #pragma unroll
          for (int e = 0; e < 4; ++e) Da[e] = 0.f;
          #pragma unroll
          for (int ks = 0; ks < 4; ++ks) {
            half8 Ba = *(const half8*)&XT[xb][mi*16 + ln][32*ks + 8*q];
            Da = __builtin_amdgcn_mfma_f32_16x16x32_f16(A4[ks], Ba, Da, 0, 0, 0);
          }
          const bool primal = (mi == 0);
          const float w_s = (stage == 1 || stage == 2) ? 2.f : 1.f;
          const float c_s = (stage < 2) ? 0.5f*dt : dt;
          half4 xn;
          #pragma unroll
          for (int r = 0; r < 4; ++r) {
            const float v = Da[r] + (primal ? b4r[r] : 0.f);
            if (stage < 3) {
              sar[r] += w_s * v;
              xn[r] = (_Float16)(sbr[r] + c_s * v);
            } else {
              const float nb = sbr[r] + (dt * (1.f/6.f)) * (sar[r] + v);
              sbr[r] = nb;
              sar[r] = 0.f;
              xn[r] = (_Float16)nb;
            }
          }
          *(half4*)&XI[mi*16 + ln][4*q] = xn;
          if (primal && q == 0) {
            const float tn = t0 + ((stage < 2) ? 0.5f*dt : dt);
            XI[ln][16] = (_Float16)tn;            // t column; cols 17..31 stay 0
          }
        }
        __syncthreads();                          // XI + XT handoff
      }
    }
  }

  // ---------------- dump state, then per-parent solve ----------------
  if (mi < 3) {
    #pragma unroll
    for (int r = 0; r < 4; ++r)
      SbL[mi*16 + ln][4*q + r] = sbr[r];
  }
  __syncthreads();

  if (mi < RPW) {
    const int p    = mi;
    const int jj   = ln;
    const int base = lane & 48;
    float c[NDIM], gv[NDIM], G[NDIM];
    #pragma unroll
    for (int i = 0; i < NDIM; ++i) c[i] = SbL[16 + 16*p + jj][i];   // J[:, jj]
    float n2 = 0.f;
    #pragma unroll
    for (int i = 0; i < NDIM; ++i) {
      gv[i] = SbL[p][i] - SbL[2 + p][i];                            // y - y*
      n2 += gv[i]*gv[i];
    }
    const float rinv = 1.f / (sqrtf(n2) + 1e-8f);
    float rhs = 0.f;
    #pragma unroll
    for (int i = 0; i < NDIM; ++i) rhs += c[i] * gv[i];
    rhs *= rinv;
    #pragma unroll
    for (int k = 0; k < NDIM; ++k) {
      float acc = (k == jj) ? 1e-6f : 0.f;
      #pragma unroll
      for (int i = 0; i < NDIM; ++i)
        acc += c[i] * __shfl(c[i], base + k, 64);
      G[k] = acc;
    }
    #pragma unroll
    for (int k = 0; k < NDIM-1; ++k) {
      const float piv  = __shfl(G[k], base + k, 64);
      const float prhs = __shfl(rhs,  base + k, 64);
      const float f = (jj > k) ? G[k] / piv : 0.f;
      #pragma unroll
      for (int cc = k; cc < NDIM; ++cc)
        G[cc] -= f * __shfl(G[cc], base + k, 64);
      rhs -= f * prhs;
    }
    float sol = 0.f;
    #pragma unroll
    for (int k = NDIM-1; k >= 0; --k) {
      const float piv = __shfl(G[k], base + k, 64);
      const float pr  = __shfl(rhs,  base + k, 64);
      const float xk  = pr / piv;
      if (jj == k) sol = xk;
      if (jj <  k) rhs -= G[k] * xk;
    }
    if (lane < NDIM)
      out[(g0 + p)*NDIM + jj] = -sol;
  }
}

extern "C" void kernel_launch(void* const* d_in, const int* in_sizes, int n_in,
                              void* d_out, int out_size, void* d_ws, size_t ws_size,
                              hipStream_t stream) {
  (void)in_sizes; (void)n_in; (void)d_ws; (void)ws_size; (void)out_size;
  flow_ode_kernel<<<dim3(512), dim3(256), 0, stream>>>(
      (const float*)d_in[0],  (const float*)d_in[1],
      (const float*)d_in[2],  (const float*)d_in[3],
      (const float*)d_in[4],  (const float*)d_in[5],
      (const float*)d_in[6],  (const float*)d_in[7],
      (const float*)d_in[8],  (const float*)d_in[9],
      (const float*)d_in[10], (const float*)d_in[11],
      (float*)d_out);
}